// Round 7
// baseline (397.241 us; speedup 1.0000x reference)
//
#include <hip/hip_runtime.h>
#include <math.h>

#define ROWS_TOTAL 8192
#define KDIM 1024
#define NPROTO 32
#define RNK 16
#define OUTD 1024
// Any np-f32 tie at the 2nd/3rd boundary requires exact d2 gap < ulp(1024)
// (=1.22e-4) + chain noise. Rows under TIE_EPS are treated as np-ties:
// top_k then keeps the LOWER INDEX of the tied pair (jax/np tie rule).
#define TIE_EPS 1.30e-4

// ---------------------------------------------------------------------------
// Kernel 1: routing. f64-exact keys k = p2 - 2*dot (error ~1e-13, tie-free).
// Wave top-3 (sorted triples butterfly). Slot0 = exact 1st.
// Slot1 = (k3-k2 < TIE_EPS) ? min-index(i2,i3) : i2   [np tie emulation]
// Weights: renormalized top-2 softmax = sigmoid((d1-d0)/t) from exact dists.
// Output per row: float4( i0(bits), i1(bits), w0, w1 ).
// ---------------------------------------------------------------------------
__global__ __launch_bounds__(256) void route_kernel(
    const float* __restrict__ x, const float* __restrict__ proto,
    const float* __restrict__ temp, float4* __restrict__ route)
{
    __shared__ float Xs[16][68];
    __shared__ float Ps[64][33];
    __shared__ double x2s[16];
    __shared__ double p2s[32];

    const int tid = threadIdx.x;
    const int rowbase = blockIdx.x * 16;
    const int frow = tid >> 4;
    const int fq   = tid & 15;
    const int c    = tid & 31;
    const int rg   = tid >> 5;

    double xsq = 0.0, p2a = 0.0, p2b = 0.0;
    double acc0 = 0.0, acc1 = 0.0;

    for (int kc = 0; kc < KDIM; kc += 64) {
        float4 xv = *(const float4*)(x + (rowbase + frow) * KDIM + kc + 4 * fq);
        xsq = fma((double)xv.x, (double)xv.x, xsq);
        xsq = fma((double)xv.y, (double)xv.y, xsq);
        xsq = fma((double)xv.z, (double)xv.z, xsq);
        xsq = fma((double)xv.w, (double)xv.w, xsq);
        *(float4*)(&Xs[frow][4 * fq]) = xv;
        float4 pa = *(const float4*)(proto + frow * KDIM + kc + 4 * fq);
        float4 pb = *(const float4*)(proto + (frow + 16) * KDIM + kc + 4 * fq);
        p2a = fma((double)pa.x, (double)pa.x, p2a);
        p2a = fma((double)pa.y, (double)pa.y, p2a);
        p2a = fma((double)pa.z, (double)pa.z, p2a);
        p2a = fma((double)pa.w, (double)pa.w, p2a);
        p2b = fma((double)pb.x, (double)pb.x, p2b);
        p2b = fma((double)pb.y, (double)pb.y, p2b);
        p2b = fma((double)pb.z, (double)pb.z, p2b);
        p2b = fma((double)pb.w, (double)pb.w, p2b);
        Ps[4 * fq + 0][frow] = pa.x;
        Ps[4 * fq + 1][frow] = pa.y;
        Ps[4 * fq + 2][frow] = pa.z;
        Ps[4 * fq + 3][frow] = pa.w;
        Ps[4 * fq + 0][frow + 16] = pb.x;
        Ps[4 * fq + 1][frow + 16] = pb.y;
        Ps[4 * fq + 2][frow + 16] = pb.z;
        Ps[4 * fq + 3][frow + 16] = pb.w;
        __syncthreads();
        #pragma unroll
        for (int k = 0; k < 64; k += 4) {
            float4 xa = *(const float4*)(&Xs[2 * rg][k]);
            float4 xb = *(const float4*)(&Xs[2 * rg + 1][k]);
            double q0 = (double)Ps[k][c],     q1 = (double)Ps[k + 1][c];
            double q2 = (double)Ps[k + 2][c], q3 = (double)Ps[k + 3][c];
            acc0 = fma((double)xa.x, q0, acc0);
            acc0 = fma((double)xa.y, q1, acc0);
            acc0 = fma((double)xa.z, q2, acc0);
            acc0 = fma((double)xa.w, q3, acc0);
            acc1 = fma((double)xb.x, q0, acc1);
            acc1 = fma((double)xb.y, q1, acc1);
            acc1 = fma((double)xb.z, q2, acc1);
            acc1 = fma((double)xb.w, q3, acc1);
        }
        __syncthreads();
    }

    #pragma unroll
    for (int m = 1; m < 16; m <<= 1) {
        xsq += __shfl_xor(xsq, m);
        p2a += __shfl_xor(p2a, m);
        p2b += __shfl_xor(p2b, m);
    }
    if (fq == 0) { x2s[frow] = xsq; p2s[frow] = p2a; p2s[frow + 16] = p2b; }
    __syncthreads();

    const double tmp = (double)fmaxf(fabsf(temp[0]), 0.1f);
    const double myp2 = p2s[c];

    #pragma unroll
    for (int which = 0; which < 2; ++which) {
        double key = myp2 - 2.0 * (which ? acc1 : acc0);
        // sorted triple (k1<=k2<=k3)
        double k1 = key, k2 = 1.0e300, k3 = 1.1e300;
        int    i1 = c,   i2 = 64,      i3 = 65;
        #pragma unroll
        for (int m = 1; m < 32; m <<= 1) {
            double b1 = __shfl_xor(k1, m), b2 = __shfl_xor(k2, m), b3 = __shfl_xor(k3, m);
            int    j1 = __shfl_xor(i1, m), j2 = __shfl_xor(i2, m), j3 = __shfl_xor(i3, m);
            bool c1 = k1 <= b1;
            double m1 = c1 ? k1 : b1, M1 = c1 ? b1 : k1;
            int   mi1 = c1 ? i1 : j1, Mi1 = c1 ? j1 : i1;
            bool c2 = k2 <= b2;
            double m2 = c2 ? k2 : b2;
            int   mi2 = c2 ? i2 : j2;
            bool c3 = k3 <= b3;
            double m3 = c3 ? k3 : b3;
            int   mi3 = c3 ? i3 : j3;
            bool c4 = M1 <= m2;
            double t2 = c4 ? M1 : m2,  T2 = c4 ? m2 : M1;
            int   ti2 = c4 ? Mi1 : mi2, Ti2 = c4 ? mi2 : Mi1;
            bool c5 = T2 <= m3;
            k1 = m1; i1 = mi1;
            k2 = t2; i2 = ti2;
            k3 = c5 ? T2 : m3; i3 = c5 ? Ti2 : mi3;
        }
        if (c == 0) {
            const int row = rowbase + 2 * rg + which;
            // np-tie emulation at the 2nd/3rd boundary: same-f32-cell pairs
            // collapse to equal dists; top_k then keeps the lower index.
            bool tie = (k3 - k2) < TIE_EPS;
            bool take3 = tie && (i3 < i2);
            double ksel = take3 ? k3 : k2;
            int    isel = take3 ? i3 : i2;
            double x2 = x2s[2 * rg + which];
            double d0 = sqrt(fmax(x2 + k1, 0.0));
            double d1 = sqrt(fmax(x2 + ksel, 0.0));
            float e  = expf((float)((d0 - d1) / tmp));   // d0<=d1 -> e<=1
            float w0 = 1.f / (1.f + e);
            route[row] = make_float4(__int_as_float(i1), __int_as_float(isel),
                                     w0, e * w0);
        }
    }
}

// ---------------------------------------------------------------------------
// Kernel 2: apply one routing slot (unchanged).
// ---------------------------------------------------------------------------
__global__ __launch_bounds__(256) void apply_kernel(
    const float* __restrict__ x, const float* __restrict__ A,
    const float* __restrict__ B, const float* __restrict__ bias,
    const float4* __restrict__ route, float* __restrict__ out, int slot)
{
    __shared__ int list[512];
    __shared__ int cnt;
    __shared__ float hl[16][20];

    const int tid = threadIdx.x;
    const int p  = blockIdx.x & 31;
    const int r0 = (blockIdx.x >> 5) << 9;

    if (tid == 0) cnt = 0;
    __syncthreads();
    for (int i = tid; i < 512; i += 256) {
        float4 rt = route[r0 + i];
        int idx = __float_as_int(slot ? rt.y : rt.x);
        if (idx == p) list[atomicAdd(&cnt, 1)] = i;
    }
    __syncthreads();
    const int n = cnt;

    const int rowi = tid >> 4;
    const int rank = tid & 15;
    const int o    = tid & 31;
    const int rsub = tid >> 5;

    for (int base = 0; base < n; base += 16) {
        const int m = min(16, n - base);
        if (rowi < m) {
            const int row = r0 + list[base + rowi];
            const float4* xr = (const float4*)(x + row * KDIM);
            const float4* br = (const float4*)(B + (p * RNK + rank) * KDIM);
            float a0 = 0.f;
            #pragma unroll 8
            for (int k = 0; k < KDIM / 4; ++k) {
                float4 xv = xr[k], bv = br[k];
                a0 = fmaf(xv.x, bv.x, fmaf(xv.y, bv.y, fmaf(xv.z, bv.z, fmaf(xv.w, bv.w, a0))));
            }
            hl[rowi][rank] = a0;
        }
        __syncthreads();
        #pragma unroll
        for (int rgi = 0; rgi < 2; ++rgi) {
            const int ri = rgi * 8 + rsub;
            if (ri < m) {
                const int row = r0 + list[base + ri];
                float4 rt = route[row];
                const float w = slot ? rt.w : rt.z;
                float4 h0 = *(const float4*)(&hl[ri][0]);
                float4 h1 = *(const float4*)(&hl[ri][4]);
                float4 h2 = *(const float4*)(&hl[ri][8]);
                float4 h3 = *(const float4*)(&hl[ri][12]);
                const float4* Ap = (const float4*)(A + p * OUTD * RNK);
                float* orow = out + row * OUTD;
                const float* brow = bias + p * OUTD;
                #pragma unroll 4
                for (int j = 0; j < 32; ++j) {
                    int oo = o + 32 * j;
                    const float4* av = Ap + oo * 4;
                    float4 a0 = av[0], a1 = av[1], a2 = av[2], a3 = av[3];
                    float acc;
                    acc = fmaf(a0.x, h0.x, fmaf(a0.y, h0.y, fmaf(a0.z, h0.z, a0.w * h0.w)));
                    acc = fmaf(a1.x, h1.x, fmaf(a1.y, h1.y, fmaf(a1.z, h1.z, fmaf(a1.w, h1.w, acc))));
                    acc = fmaf(a2.x, h2.x, fmaf(a2.y, h2.y, fmaf(a2.z, h2.z, fmaf(a2.w, h2.w, acc))));
                    acc = fmaf(a3.x, h3.x, fmaf(a3.y, h3.y, fmaf(a3.z, h3.z, fmaf(a3.w, h3.w, acc))));
                    acc += brow[oo];
                    float v = w * acc;
                    if (slot) orow[oo] += v;
                    else      orow[oo] = v;
                }
            }
        }
        __syncthreads();
    }
}

extern "C" void kernel_launch(void* const* d_in, const int* in_sizes, int n_in,
                              void* d_out, int out_size, void* d_ws, size_t ws_size,
                              hipStream_t stream) {
    const float* x     = (const float*)d_in[0];
    const float* proto = (const float*)d_in[1];
    const float* B     = (const float*)d_in[2];
    const float* A     = (const float*)d_in[3];
    const float* bias  = (const float*)d_in[4];
    const float* temp  = (const float*)d_in[5];
    float* out = (float*)d_out;

    float4* route = (float4*)d_ws;   // 8192 * 16B = 128 KB

    route_kernel<<<ROWS_TOTAL / 16, 256, 0, stream>>>(x, proto, temp, route);
    apply_kernel<<<NPROTO * 16, 256, 0, stream>>>(x, A, B, bias, route, out, 0);
    apply_kernel<<<NPROTO * 16, 256, 0, stream>>>(x, A, B, bias, route, out, 1);
}

// Round 8
// 248.200 us; speedup vs baseline: 1.6005x; 1.6005x over previous
//
#include <hip/hip_runtime.h>
#include <math.h>

#define ROWS_TOTAL 8192
#define KDIM 1024
#define NPROTO 32
#define RNK 16
#define OUTD 1024
#define TIE_EPS 1.30e-4

// ---------------------------------------------------------------------------
// Kernel 1: routing (numerics identical to the PASSING round-7 kernel).
// Adds per-block LDS histogram of chosen protos -> global counts[64]
// (slot0: 0..31, slot1: 32..63) for the compaction passes.
// ---------------------------------------------------------------------------
__global__ __launch_bounds__(256) void route_kernel(
    const float* __restrict__ x, const float* __restrict__ proto,
    const float* __restrict__ temp, float4* __restrict__ route,
    int* __restrict__ counts)
{
    __shared__ float Xs[16][68];
    __shared__ float Ps[64][33];
    __shared__ double x2s[16];
    __shared__ double p2s[32];
    __shared__ int lcnt[64];

    const int tid = threadIdx.x;
    const int rowbase = blockIdx.x * 16;
    const int frow = tid >> 4;
    const int fq   = tid & 15;
    const int c    = tid & 31;
    const int rg   = tid >> 5;

    if (tid < 64) lcnt[tid] = 0;

    double xsq = 0.0, p2a = 0.0, p2b = 0.0;
    double acc0 = 0.0, acc1 = 0.0;

    for (int kc = 0; kc < KDIM; kc += 64) {
        float4 xv = *(const float4*)(x + (rowbase + frow) * KDIM + kc + 4 * fq);
        xsq = fma((double)xv.x, (double)xv.x, xsq);
        xsq = fma((double)xv.y, (double)xv.y, xsq);
        xsq = fma((double)xv.z, (double)xv.z, xsq);
        xsq = fma((double)xv.w, (double)xv.w, xsq);
        *(float4*)(&Xs[frow][4 * fq]) = xv;
        float4 pa = *(const float4*)(proto + frow * KDIM + kc + 4 * fq);
        float4 pb = *(const float4*)(proto + (frow + 16) * KDIM + kc + 4 * fq);
        p2a = fma((double)pa.x, (double)pa.x, p2a);
        p2a = fma((double)pa.y, (double)pa.y, p2a);
        p2a = fma((double)pa.z, (double)pa.z, p2a);
        p2a = fma((double)pa.w, (double)pa.w, p2a);
        p2b = fma((double)pb.x, (double)pb.x, p2b);
        p2b = fma((double)pb.y, (double)pb.y, p2b);
        p2b = fma((double)pb.z, (double)pb.z, p2b);
        p2b = fma((double)pb.w, (double)pb.w, p2b);
        Ps[4 * fq + 0][frow] = pa.x;
        Ps[4 * fq + 1][frow] = pa.y;
        Ps[4 * fq + 2][frow] = pa.z;
        Ps[4 * fq + 3][frow] = pa.w;
        Ps[4 * fq + 0][frow + 16] = pb.x;
        Ps[4 * fq + 1][frow + 16] = pb.y;
        Ps[4 * fq + 2][frow + 16] = pb.z;
        Ps[4 * fq + 3][frow + 16] = pb.w;
        __syncthreads();
        #pragma unroll
        for (int k = 0; k < 64; k += 4) {
            float4 xa = *(const float4*)(&Xs[2 * rg][k]);
            float4 xb = *(const float4*)(&Xs[2 * rg + 1][k]);
            double q0 = (double)Ps[k][c],     q1 = (double)Ps[k + 1][c];
            double q2 = (double)Ps[k + 2][c], q3 = (double)Ps[k + 3][c];
            acc0 = fma((double)xa.x, q0, acc0);
            acc0 = fma((double)xa.y, q1, acc0);
            acc0 = fma((double)xa.z, q2, acc0);
            acc0 = fma((double)xa.w, q3, acc0);
            acc1 = fma((double)xb.x, q0, acc1);
            acc1 = fma((double)xb.y, q1, acc1);
            acc1 = fma((double)xb.z, q2, acc1);
            acc1 = fma((double)xb.w, q3, acc1);
        }
        __syncthreads();
    }

    #pragma unroll
    for (int m = 1; m < 16; m <<= 1) {
        xsq += __shfl_xor(xsq, m);
        p2a += __shfl_xor(p2a, m);
        p2b += __shfl_xor(p2b, m);
    }
    if (fq == 0) { x2s[frow] = xsq; p2s[frow] = p2a; p2s[frow + 16] = p2b; }
    __syncthreads();

    const double tmp = (double)fmaxf(fabsf(temp[0]), 0.1f);
    const double myp2 = p2s[c];

    #pragma unroll
    for (int which = 0; which < 2; ++which) {
        double key = myp2 - 2.0 * (which ? acc1 : acc0);
        double k1 = key, k2 = 1.0e300, k3 = 1.1e300;
        int    i1 = c,   i2 = 64,      i3 = 65;
        #pragma unroll
        for (int m = 1; m < 32; m <<= 1) {
            double b1 = __shfl_xor(k1, m), b2 = __shfl_xor(k2, m), b3 = __shfl_xor(k3, m);
            int    j1 = __shfl_xor(i1, m), j2 = __shfl_xor(i2, m), j3 = __shfl_xor(i3, m);
            bool c1 = k1 <= b1;
            double m1 = c1 ? k1 : b1, M1 = c1 ? b1 : k1;
            int   mi1 = c1 ? i1 : j1, Mi1 = c1 ? j1 : i1;
            bool c2 = k2 <= b2;
            double m2 = c2 ? k2 : b2;
            int   mi2 = c2 ? i2 : j2;
            bool c3 = k3 <= b3;
            double m3 = c3 ? k3 : b3;
            int   mi3 = c3 ? i3 : j3;
            bool c4 = M1 <= m2;
            double t2 = c4 ? M1 : m2,  T2 = c4 ? m2 : M1;
            int   ti2 = c4 ? Mi1 : mi2, Ti2 = c4 ? mi2 : Mi1;
            bool c5 = T2 <= m3;
            k1 = m1; i1 = mi1;
            k2 = t2; i2 = ti2;
            k3 = c5 ? T2 : m3; i3 = c5 ? Ti2 : mi3;
        }
        if (c == 0) {
            const int row = rowbase + 2 * rg + which;
            bool tie = (k3 - k2) < TIE_EPS;
            bool take3 = tie && (i3 < i2);
            double ksel = take3 ? k3 : k2;
            int    isel = take3 ? i3 : i2;
            double x2 = x2s[2 * rg + which];
            double d0 = sqrt(fmax(x2 + k1, 0.0));
            double d1 = sqrt(fmax(x2 + ksel, 0.0));
            float e  = expf((float)((d0 - d1) / tmp));
            float w0 = 1.f / (1.f + e);
            route[row] = make_float4(__int_as_float(i1), __int_as_float(isel),
                                     w0, e * w0);
            atomicAdd(&lcnt[i1], 1);
            atomicAdd(&lcnt[32 + isel], 1);
        }
    }
    __syncthreads();
    if (tid < 64) atomicAdd(&counts[tid], lcnt[tid]);
}

// ---------------------------------------------------------------------------
// Scan: counts[64] -> exclusive offsets per 32-slot segment (cursor bases).
// ---------------------------------------------------------------------------
__global__ __launch_bounds__(64) void scan_kernel(int* __restrict__ counts)
{
    const int tid = threadIdx.x;
    int v = counts[tid];
    int sum = v;
    #pragma unroll
    for (int off = 1; off < 32; off <<= 1) {
        int u = __shfl_up(sum, off, 32);
        if ((tid & 31) >= off) sum += u;
    }
    counts[tid] = sum - v;   // exclusive prefix within each slot segment
}

// ---------------------------------------------------------------------------
// Scatter: rows into per-proto contiguous lists (proto-sorted compaction).
// ---------------------------------------------------------------------------
__global__ __launch_bounds__(256) void scatter_kernel(
    const float4* __restrict__ route, int* __restrict__ counts,
    int* __restrict__ rowlist0, int* __restrict__ rowlist1)
{
    __shared__ int lcnt[64];
    __shared__ int gbase[64];
    const int tid = threadIdx.x;
    const int i = blockIdx.x * 256 + tid;
    if (tid < 64) lcnt[tid] = 0;
    __syncthreads();
    float4 rt = route[i];
    int p0 = __float_as_int(rt.x);
    int p1 = __float_as_int(rt.y);
    int lp0 = atomicAdd(&lcnt[p0], 1);
    int lp1 = atomicAdd(&lcnt[32 + p1], 1);
    __syncthreads();
    if (tid < 64) gbase[tid] = atomicAdd(&counts[tid], lcnt[tid]);
    __syncthreads();
    rowlist0[gbase[p0] + lp0] = i;
    rowlist1[gbase[32 + p1] + lp1] = i;
}

// ---------------------------------------------------------------------------
// Apply v2: flat chunks of 8 rows from the proto-sorted list. 1024 blocks,
// 256 threads. Stage 8 x-rows in LDS (coalesced); h-phase (row,rank,ks) with
// 4 independent FMA chains + 1 shfl reduce; y-phase float4 A*h + bias,
// slot0 stores w*y, slot1 accumulates (race-free: one writer per row).
// ---------------------------------------------------------------------------
__global__ __launch_bounds__(256) void apply2_kernel(
    const float* __restrict__ x, const float* __restrict__ A,
    const float* __restrict__ B, const float* __restrict__ bias,
    const float4* __restrict__ route, const int* __restrict__ rowlist,
    float* __restrict__ out, int slot)
{
    __shared__ __align__(16) float Xs[8 * KDIM];   // 32 KB
    __shared__ __align__(16) float hs[8][16];
    __shared__ int rows[8];
    __shared__ int protos[8];
    __shared__ float wrow[8];

    const int tid = threadIdx.x;
    const int base = blockIdx.x * 8;

    if (tid < 8) {
        int row = rowlist[base + tid];
        rows[tid] = row;
        float4 rt = route[row];
        protos[tid] = __float_as_int(slot ? rt.y : rt.x);
        wrow[tid] = slot ? rt.w : rt.z;
    }
    __syncthreads();

    // stage x rows: instruction i loads row i fully (256 x float4 = 4KB)
    #pragma unroll
    for (int i = 0; i < 8; ++i) {
        float4 v = *(const float4*)(x + rows[i] * KDIM + tid * 4);
        *(float4*)(&Xs[i * KDIM + tid * 4]) = v;
    }
    __syncthreads();

    // ---- h phase: thread = (row=tid>>5, rank=(tid>>1)&15, ks=tid&1) ----
    {
        const int hrow = tid >> 5, hrank = (tid >> 1) & 15, hks = tid & 1;
        const float* Brow = B + (protos[hrow] * RNK + hrank) * KDIM;
        const float* Xrow = &Xs[hrow * KDIM];
        float a0 = 0.f, a1 = 0.f, a2 = 0.f, a3 = 0.f;
        #pragma unroll 4
        for (int i = 0; i < 32; ++i) {
            const int f0 = hks + 8 * i;      // float4 indices f0, f0+2, +4, +6
            float4 xv0 = *(const float4*)(Xrow + 4 * (f0 + 0));
            float4 bv0 = *(const float4*)(Brow + 4 * (f0 + 0));
            float4 xv1 = *(const float4*)(Xrow + 4 * (f0 + 2));
            float4 bv1 = *(const float4*)(Brow + 4 * (f0 + 2));
            float4 xv2 = *(const float4*)(Xrow + 4 * (f0 + 4));
            float4 bv2 = *(const float4*)(Brow + 4 * (f0 + 4));
            float4 xv3 = *(const float4*)(Xrow + 4 * (f0 + 6));
            float4 bv3 = *(const float4*)(Brow + 4 * (f0 + 6));
            a0 = fmaf(xv0.x, bv0.x, fmaf(xv0.y, bv0.y, fmaf(xv0.z, bv0.z, fmaf(xv0.w, bv0.w, a0))));
            a1 = fmaf(xv1.x, bv1.x, fmaf(xv1.y, bv1.y, fmaf(xv1.z, bv1.z, fmaf(xv1.w, bv1.w, a1))));
            a2 = fmaf(xv2.x, bv2.x, fmaf(xv2.y, bv2.y, fmaf(xv2.z, bv2.z, fmaf(xv2.w, bv2.w, a2))));
            a3 = fmaf(xv3.x, bv3.x, fmaf(xv3.y, bv3.y, fmaf(xv3.z, bv3.z, fmaf(xv3.w, bv3.w, a3))));
        }
        float hsum = (a0 + a1) + (a2 + a3);
        hsum += __shfl_xor(hsum, 1);
        if (hks == 0) hs[hrow][hrank] = hsum;
    }
    __syncthreads();

    // ---- y phase: thread = (row=tid>>5, o=tid&31); 8 float4 outs each ----
    {
        const int yrow = tid >> 5, o = tid & 31;
        const int p = protos[yrow];
        const float wgt = wrow[yrow];
        const float4* Ap = (const float4*)(A + p * OUTD * RNK);
        const float4* bp = (const float4*)(bias + p * OUTD);
        float4 h0 = *(const float4*)(&hs[yrow][0]);
        float4 h1 = *(const float4*)(&hs[yrow][4]);
        float4 h2 = *(const float4*)(&hs[yrow][8]);
        float4 h3 = *(const float4*)(&hs[yrow][12]);
        float* orow = out + rows[yrow] * OUTD;
        #pragma unroll
        for (int j = 0; j < 8; ++j) {
            const int f4 = j * 32 + o;       // out float4 index
            float4 bb = bp[f4];
            float r[4];
            #pragma unroll
            for (int t = 0; t < 4; ++t) {
                const float4* av = Ap + (f4 * 4 + t) * 4;
                float4 q0 = av[0], q1 = av[1], q2 = av[2], q3 = av[3];
                float acc;
                acc = fmaf(q0.x, h0.x, fmaf(q0.y, h0.y, fmaf(q0.z, h0.z, q0.w * h0.w)));
                acc = fmaf(q1.x, h1.x, fmaf(q1.y, h1.y, fmaf(q1.z, h1.z, fmaf(q1.w, h1.w, acc))));
                acc = fmaf(q2.x, h2.x, fmaf(q2.y, h2.y, fmaf(q2.z, h2.z, fmaf(q2.w, h2.w, acc))));
                acc = fmaf(q3.x, h3.x, fmaf(q3.y, h3.y, fmaf(q3.z, h3.z, fmaf(q3.w, h3.w, acc))));
                r[t] = acc;
            }
            float4 v = make_float4(wgt * (r[0] + bb.x), wgt * (r[1] + bb.y),
                                   wgt * (r[2] + bb.z), wgt * (r[3] + bb.w));
            float4* dst = (float4*)(orow + f4 * 4);
            if (slot) {
                float4 old = *dst;
                v.x += old.x; v.y += old.y; v.z += old.z; v.w += old.w;
            }
            *dst = v;
        }
    }
}

extern "C" void kernel_launch(void* const* d_in, const int* in_sizes, int n_in,
                              void* d_out, int out_size, void* d_ws, size_t ws_size,
                              hipStream_t stream) {
    const float* x     = (const float*)d_in[0];
    const float* proto = (const float*)d_in[1];
    const float* B     = (const float*)d_in[2];
    const float* A     = (const float*)d_in[3];
    const float* bias  = (const float*)d_in[4];
    const float* temp  = (const float*)d_in[5];
    float* out = (float*)d_out;

    float4* route   = (float4*)d_ws;                        // 128 KB
    int* rowlist0   = (int*)((char*)d_ws + 131072);         // 32 KB
    int* rowlist1   = rowlist0 + ROWS_TOTAL;                // 32 KB
    int* counts     = rowlist1 + ROWS_TOTAL;                // 256 B

    hipMemsetAsync(counts, 0, 64 * sizeof(int), stream);
    route_kernel<<<ROWS_TOTAL / 16, 256, 0, stream>>>(x, proto, temp, route, counts);
    scan_kernel<<<1, 64, 0, stream>>>(counts);
    scatter_kernel<<<ROWS_TOTAL / 256, 256, 0, stream>>>(route, counts, rowlist0, rowlist1);
    apply2_kernel<<<ROWS_TOTAL / 8, 256, 0, stream>>>(x, A, B, bias, route, rowlist0, out, 0);
    apply2_kernel<<<ROWS_TOTAL / 8, 256, 0, stream>>>(x, A, B, bias, route, rowlist1, out, 1);
}